// Round 17
// baseline (48.971 us; speedup 1.0000x reference)
//
#include <hip/hip_runtime.h>

#define MXN 2048   // MX == NY == 2048
#define DD  256
#define KK  100
#define KP  128    // K padded to MFMA granularity
#define NB  8

typedef __attribute__((ext_vector_type(8))) __bf16 bf16x8;
typedef __attribute__((ext_vector_type(4))) float  f32x4;

// ---------------------------------------------------------------------------
// Kernel 1: XA = bf16(X @ A), sqX[r] = sum_k XA[r][k]^2.
// Inline At build v3: thread u=t&127 owns d-pair (2u,2u+1), k-half h=t>>7.
// Reads 2x25 aligned float2 from A rows 2u/2u+1, packs the two columns'
// bf16 into one u32 (v_cvt_pk_bf16_f32), 50 ds_write_b32 (lane stride 4B ->
// 2 lanes/bank = free). Halves the LDS-write issue of R15's 100 b16 writes.
// MFMA body unchanged (R4-proven).
// ---------------------------------------------------------------------------
__global__ __launch_bounds__(256) void k_proj(
    const float* __restrict__ X, const float* __restrict__ Y,
    const float* __restrict__ A,
    unsigned short* __restrict__ XAo, unsigned short* __restrict__ YAo,
    float* __restrict__ sqX, float* __restrict__ sqY)
{
  __shared__ __align__(16) unsigned short Ash[128 * 256]; // [k][d] swizzled, 64 KB

  const int bid = blockIdx.x;
  const bool isY = bid >= 256;
  const int row0 = (bid & 255) * 64;
  const float* __restrict__ src = isY ? Y : X;
  unsigned short* __restrict__ dst = isY ? YAo : XAo;
  float* __restrict__ sqdst = isY ? sqY : sqX;
  const int t = threadIdx.x;

  // Zero-fill pad rows k in [100,128): bytes [51200, 65536), 56 B/thread.
  {
    char* p = (char*)Ash + 51200 + t * 56;
#pragma unroll
    for (int i = 0; i < 7; ++i)
      *reinterpret_cast<unsigned long long*>(p + i * 8) = 0ull;
  }
  // b32-packed transpose: d-pair (2u, 2u+1), k in [50h, 50h+50).
  {
    const int u = t & 127;
    const int k0 = (t >> 7) * 50;
    const float* r0 = A + (size_t)(2 * u) * KK + k0;      // 8-B aligned
    const float* r1 = A + (size_t)(2 * u + 1) * KK + k0;
#pragma unroll
    for (int j = 0; j < 25; ++j) {
      float2 a0 = *reinterpret_cast<const float2*>(r0 + j * 2);
      float2 a1 = *reinterpret_cast<const float2*>(r1 + j * 2);
#pragma unroll
      for (int q = 0; q < 2; ++q) {
        int k = k0 + j * 2 + q;
        union { __bf16 b[2]; unsigned w; } cv;
        cv.b[0] = (__bf16)(q ? a0.y : a0.x);   // d = 2u
        cv.b[1] = (__bf16)(q ? a1.y : a1.x);   // d = 2u+1
        int byte = (k * 512 + u * 4) ^ ((k & 7) << 4);
        *reinterpret_cast<unsigned*>((char*)Ash + byte) = cv.w;
      }
    }
  }
  __syncthreads();

  const int w = t >> 6, l = t & 63;
  const int lr = l & 15, lk8 = (l >> 4) * 8;
  const int rowA = row0 + w * 16 + lr;

  f32x4 acc[8];
#pragma unroll
  for (int j = 0; j < 8; ++j) acc[j] = (f32x4){0.f, 0.f, 0.f, 0.f};

#pragma unroll
  for (int ks = 0; ks < 8; ++ks) {
    const int d = ks * 32 + lk8;
    const float* px = src + (size_t)rowA * DD + d;
    float4 v0 = *reinterpret_cast<const float4*>(px);
    float4 v1 = *reinterpret_cast<const float4*>(px + 4);
    bf16x8 af;
    af[0] = (__bf16)v0.x; af[1] = (__bf16)v0.y; af[2] = (__bf16)v0.z; af[3] = (__bf16)v0.w;
    af[4] = (__bf16)v1.x; af[5] = (__bf16)v1.y; af[6] = (__bf16)v1.z; af[7] = (__bf16)v1.w;
#pragma unroll
    for (int nf = 0; nf < 8; ++nf) {
      const int kq = nf * 16 + lr;
      bf16x8 bf = *reinterpret_cast<bf16x8*>(
          (char*)Ash + ((kq * 512 + d * 2) ^ ((kq & 7) << 4)));
      acc[nf] = __builtin_amdgcn_mfma_f32_16x16x32_bf16(af, bf, acc[nf], 0, 0, 0);
    }
  }

  float sq[4] = {0.f, 0.f, 0.f, 0.f};
#pragma unroll
  for (int nf = 0; nf < 8; ++nf)
#pragma unroll
    for (int reg = 0; reg < 4; ++reg) {
      union { __bf16 b; unsigned short u; } cv;
      cv.b = (__bf16)acc[nf][reg];
      float vq = (float)cv.b;
      int r = row0 + w * 16 + ((l >> 4) << 2) + reg;
      dst[(size_t)r * KP + nf * 16 + lr] = cv.u;
      sq[reg] += vq * vq;
    }
#pragma unroll
  for (int reg = 0; reg < 4; ++reg) {
    float s = sq[reg];
    s += __shfl_xor(s, 1);
    s += __shfl_xor(s, 2);
    s += __shfl_xor(s, 4);
    s += __shfl_xor(s, 8);
    if (lr == 0)
      sqdst[row0 + w * 16 + ((l >> 4) << 2) + reg] = s;
  }
}

// ---------------------------------------------------------------------------
// Kernel 2: R10 body exactly, PLAIN stores (NT stores reverted: they bypass
// L2 and race with the harness's cached poison-fill dirty lines — post-
// timing divergence in R16). T_cross = 28.0 us, empirical floor across 7
// structural variants.
// ---------------------------------------------------------------------------
__global__ __launch_bounds__(256, 4) void k_cross(
    const unsigned short* __restrict__ XA, const unsigned short* __restrict__ YA,
    const float* __restrict__ sqX, const float* __restrict__ sqY,
    float* __restrict__ out)
{
  __shared__ __align__(16) unsigned short Xsh[128 * 128];  // 32 KB swizzled

  const int bid = blockIdx.x;
  const int b   = bid & 7;             // batch -> XCD pin
  const int sh_ = bid >> 3;            // 0..127
  const int n0  = (sh_ >> 1) * 32;     // 64 strips per batch
  const int mh  = (sh_ & 1) * 8;       // m-tile half: tiles [mh, mh+8)
  const int t = threadIdx.x;
  const int w = t >> 6, l = t & 63;
  const int m_w = w * 32;              // wave's m-offset within a 128-tile
  const int lr = l & 15, lk = (l >> 4) * 8;

  bf16x8 yf[2][4];
#pragma unroll
  for (int i = 0; i < 2; ++i)
#pragma unroll
    for (int ks = 0; ks < 4; ++ks)
      yf[i][ks] = *reinterpret_cast<const bf16x8*>(
          YA + ((size_t)(b * MXN + n0 + i * 16 + lr) * KP + ks * 32 + lk));

  float syv[2][4];
#pragma unroll
  for (int i = 0; i < 2; ++i)
#pragma unroll
    for (int reg = 0; reg < 4; ++reg)
      syv[i][reg] = sqY[b * MXN + n0 + i * 16 + ((l >> 4) << 2) + reg];

  bf16x8 xr[8];
#pragma unroll
  for (int i = 0; i < 8; ++i) {
    int ch = i * 256 + t;
    int row = ch >> 4, c = ch & 15;
    xr[i] = *reinterpret_cast<const bf16x8*>(
        XA + ((size_t)(b * MXN + mh * 128 + row) * KP + c * 8));
  }

  for (int it = 0; it < 8; ++it) {
    const int mt = mh + it;

    asm volatile("s_waitcnt lgkmcnt(0)" ::: "memory");
    __builtin_amdgcn_s_barrier();
    asm volatile("" ::: "memory");

#pragma unroll
    for (int i = 0; i < 8; ++i) {
      int ch = i * 256 + t;
      int row = ch >> 4, c = ch & 15;
      int byte = (row * 256 + c * 16) ^ ((row & 7) << 4);
      *reinterpret_cast<bf16x8*>((char*)Xsh + byte) = xr[i];
    }

    asm volatile("s_waitcnt lgkmcnt(0)" ::: "memory");
    __builtin_amdgcn_s_barrier();
    asm volatile("" ::: "memory");

    if (it < 7) {
#pragma unroll
      for (int i = 0; i < 8; ++i) {
        int ch = i * 256 + t;
        int row = ch >> 4, c = ch & 15;
        xr[i] = *reinterpret_cast<const bf16x8*>(
            XA + ((size_t)(b * MXN + (mt + 1) * 128 + row) * KP + c * 8));
      }
    }

    f32x4 acc[2][2];
#pragma unroll
    for (int i = 0; i < 2; ++i)
#pragma unroll
      for (int j = 0; j < 2; ++j) acc[i][j] = (f32x4){0.f, 0.f, 0.f, 0.f};

#pragma unroll
    for (int ks = 0; ks < 4; ++ks) {
      const int d2 = ks * 64 + lk * 2;   // byte offset within row
      int rm0 = m_w + lr, rm1 = m_w + 16 + lr;
      bf16x8 b0 = *reinterpret_cast<bf16x8*>(
          (char*)Xsh + ((rm0 * 256 + d2) ^ ((rm0 & 7) << 4)));
      bf16x8 b1 = *reinterpret_cast<bf16x8*>(
          (char*)Xsh + ((rm1 * 256 + d2) ^ ((rm1 & 7) << 4)));
      acc[0][0] = __builtin_amdgcn_mfma_f32_16x16x32_bf16(yf[0][ks], b0, acc[0][0], 0, 0, 0);
      acc[0][1] = __builtin_amdgcn_mfma_f32_16x16x32_bf16(yf[0][ks], b1, acc[0][1], 0, 0, 0);
      acc[1][0] = __builtin_amdgcn_mfma_f32_16x16x32_bf16(yf[1][ks], b0, acc[1][0], 0, 0, 0);
      acc[1][1] = __builtin_amdgcn_mfma_f32_16x16x32_bf16(yf[1][ks], b1, acc[1][1], 0, 0, 0);
    }

    float sx0 = sqX[b * MXN + mt * 128 + m_w + lr];
    float sx1 = sqX[b * MXN + mt * 128 + m_w + 16 + lr];
#pragma unroll
    for (int i = 0; i < 2; ++i)
#pragma unroll
      for (int reg = 0; reg < 4; ++reg) {
        int n = n0 + i * 16 + ((l >> 4) << 2) + reg;
        size_t obase = ((size_t)b * MXN + n) * MXN + mt * 128 + m_w;
        float v0 = syv[i][reg] + sx0 - 2.0f * acc[i][0][reg];
        float v1 = syv[i][reg] + sx1 - 2.0f * acc[i][1][reg];
        out[obase + lr]      = v0 > 0.f ? v0 : 0.f;
        out[obase + 16 + lr] = v1 > 0.f ? v1 : 0.f;
      }
  }
}

extern "C" void kernel_launch(void* const* d_in, const int* in_sizes, int n_in,
                              void* d_out, int out_size, void* d_ws, size_t ws_size,
                              hipStream_t stream) {
  const float* X = (const float*)d_in[0];   // (8, 2048, 256)
  const float* Y = (const float*)d_in[1];   // (8, 2048, 256)
  const float* A = (const float*)d_in[2];   // (256, 100)
  float* out = (float*)d_out;               // (8, 2048, 2048)

  char* ws = (char*)d_ws;
  const size_t ROWS = (size_t)NB * MXN;     // 16384
  unsigned short* XAw = (unsigned short*)ws;                        // 4 MB
  unsigned short* YAw = (unsigned short*)(ws + ROWS * KP * 2);      // 4 MB
  float* sqX = (float*)(ws + 2 * ROWS * KP * 2);                    // 64 KB
  float* sqY = (float*)(ws + 2 * ROWS * KP * 2 + ROWS * 4);         // 64 KB

  k_proj<<<512, 256, 0, stream>>>(X, Y, A, XAw, YAw, sqX, sqY);
  k_cross<<<1024, 256, 0, stream>>>(XAw, YAw, sqX, sqY, out);
}

// Round 19
// 46.806 us; speedup vs baseline: 1.0463x; 1.0463x over previous
//
#include <hip/hip_runtime.h>

#define MXN 2048   // MX == NY == 2048
#define DD  256
#define KK  100
#define KP  128    // K padded to MFMA granularity
#define NB  8

typedef __attribute__((ext_vector_type(8))) __bf16 bf16x8;
typedef __attribute__((ext_vector_type(4))) float  f32x4;

// ---------------------------------------------------------------------------
// Kernel 1: XA = bf16(X @ A), sqX[r] = sum_k XA[r][k]^2.  (R15 body — best.)
// Inline bank-safe At build: thread t owns column d = t, reads A's contiguous
// row t (25 x float4), scatters down column t of swizzled Ash[k][d]
// (lane byte-stride 2 -> 2 lanes/bank = free). Measured optimum of the three
// build variants (R14 row-partitioned: bank conflicts; R17 b32-packed:
// doubled uncoalesced global loads).
// ---------------------------------------------------------------------------
__global__ __launch_bounds__(256) void k_proj(
    const float* __restrict__ X, const float* __restrict__ Y,
    const float* __restrict__ A,
    unsigned short* __restrict__ XAo, unsigned short* __restrict__ YAo,
    float* __restrict__ sqX, float* __restrict__ sqY)
{
  __shared__ __align__(16) unsigned short Ash[128 * 256]; // [k][d] swizzled, 64 KB

  const int bid = blockIdx.x;
  const bool isY = bid >= 256;
  const int row0 = (bid & 255) * 64;
  const float* __restrict__ src = isY ? Y : X;
  unsigned short* __restrict__ dst = isY ? YAo : XAo;
  float* __restrict__ sqdst = isY ? sqY : sqX;
  const int t = threadIdx.x;

  // Zero-fill pad rows k in [100,128): bytes [51200, 65536), 56 B/thread.
  {
    char* p = (char*)Ash + 51200 + t * 56;
#pragma unroll
    for (int i = 0; i < 7; ++i)
      *reinterpret_cast<unsigned long long*>(p + i * 8) = 0ull;
  }
  // Thread t = column d: read A[t][0..99] contiguous, scatter down column t.
  {
    const float4* arow = reinterpret_cast<const float4*>(A + t * KK); // 400 B
#pragma unroll
    for (int j = 0; j < 25; ++j) {
      float4 v = arow[j];
#pragma unroll
      for (int q = 0; q < 4; ++q) {
        int k = j * 4 + q;
        union { __bf16 b; unsigned short u; } cv;
        cv.b = (__bf16)((q == 0) ? v.x : (q == 1) ? v.y : (q == 2) ? v.z : v.w);
        int byte = (k * 512 + t * 2) ^ ((k & 7) << 4);
        *reinterpret_cast<unsigned short*>((char*)Ash + byte) = cv.u;
      }
    }
  }
  __syncthreads();

  const int w = t >> 6, l = t & 63;
  const int lr = l & 15, lk8 = (l >> 4) * 8;
  const int rowA = row0 + w * 16 + lr;

  f32x4 acc[8];
#pragma unroll
  for (int j = 0; j < 8; ++j) acc[j] = (f32x4){0.f, 0.f, 0.f, 0.f};

#pragma unroll
  for (int ks = 0; ks < 8; ++ks) {
    const int d = ks * 32 + lk8;
    const float* px = src + (size_t)rowA * DD + d;
    float4 v0 = *reinterpret_cast<const float4*>(px);
    float4 v1 = *reinterpret_cast<const float4*>(px + 4);
    bf16x8 af;
    af[0] = (__bf16)v0.x; af[1] = (__bf16)v0.y; af[2] = (__bf16)v0.z; af[3] = (__bf16)v0.w;
    af[4] = (__bf16)v1.x; af[5] = (__bf16)v1.y; af[6] = (__bf16)v1.z; af[7] = (__bf16)v1.w;
#pragma unroll
    for (int nf = 0; nf < 8; ++nf) {
      const int kq = nf * 16 + lr;
      bf16x8 bf = *reinterpret_cast<bf16x8*>(
          (char*)Ash + ((kq * 512 + d * 2) ^ ((kq & 7) << 4)));
      acc[nf] = __builtin_amdgcn_mfma_f32_16x16x32_bf16(af, bf, acc[nf], 0, 0, 0);
    }
  }

  float sq[4] = {0.f, 0.f, 0.f, 0.f};
#pragma unroll
  for (int nf = 0; nf < 8; ++nf)
#pragma unroll
    for (int reg = 0; reg < 4; ++reg) {
      union { __bf16 b; unsigned short u; } cv;
      cv.b = (__bf16)acc[nf][reg];
      float vq = (float)cv.b;
      int r = row0 + w * 16 + ((l >> 4) << 2) + reg;
      dst[(size_t)r * KP + nf * 16 + lr] = cv.u;
      sq[reg] += vq * vq;
    }
#pragma unroll
  for (int reg = 0; reg < 4; ++reg) {
    float s = sq[reg];
    s += __shfl_xor(s, 1);
    s += __shfl_xor(s, 2);
    s += __shfl_xor(s, 4);
    s += __shfl_xor(s, 8);
    if (lr == 0)
      sqdst[row0 + w * 16 + ((l >> 4) << 2) + reg] = s;
  }
}

// ---------------------------------------------------------------------------
// Kernel 2: strip-persistent cross term, R10 grid (1024 blocks = batch x
// 32-row n-strip x m-half; 4 blocks/CU; single-buffer Xsh + reg prefetch)
// with CONVENTIONAL __syncthreads() barriers. The hand-rolled lgkm-only
// barrier raced intermittently (R16/R18 post-timing divergence: the same
// source passed at R15); full vmcnt+lgkm drain was measured neutral on this
// family (R4 47.9 full-drain vs R8 48.4 lgkm-only). Correctness over 1 us.
// ---------------------------------------------------------------------------
__global__ __launch_bounds__(256, 4) void k_cross(
    const unsigned short* __restrict__ XA, const unsigned short* __restrict__ YA,
    const float* __restrict__ sqX, const float* __restrict__ sqY,
    float* __restrict__ out)
{
  __shared__ __align__(16) unsigned short Xsh[128 * 128];  // 32 KB swizzled

  const int bid = blockIdx.x;
  const int b   = bid & 7;             // batch -> XCD pin
  const int sh_ = bid >> 3;            // 0..127
  const int n0  = (sh_ >> 1) * 32;     // 64 strips per batch
  const int mh  = (sh_ & 1) * 8;       // m-tile half: tiles [mh, mh+8)
  const int t = threadIdx.x;
  const int w = t >> 6, l = t & 63;
  const int m_w = w * 32;              // wave's m-offset within a 128-tile
  const int lr = l & 15, lk = (l >> 4) * 8;

  bf16x8 yf[2][4];
#pragma unroll
  for (int i = 0; i < 2; ++i)
#pragma unroll
    for (int ks = 0; ks < 4; ++ks)
      yf[i][ks] = *reinterpret_cast<const bf16x8*>(
          YA + ((size_t)(b * MXN + n0 + i * 16 + lr) * KP + ks * 32 + lk));

  float syv[2][4];
#pragma unroll
  for (int i = 0; i < 2; ++i)
#pragma unroll
    for (int reg = 0; reg < 4; ++reg)
      syv[i][reg] = sqY[b * MXN + n0 + i * 16 + ((l >> 4) << 2) + reg];

  bf16x8 xr[8];
#pragma unroll
  for (int i = 0; i < 8; ++i) {
    int ch = i * 256 + t;
    int row = ch >> 4, c = ch & 15;
    xr[i] = *reinterpret_cast<const bf16x8*>(
        XA + ((size_t)(b * MXN + mh * 128 + row) * KP + c * 8));
  }

  for (int it = 0; it < 8; ++it) {
    const int mt = mh + it;

    __syncthreads();                    // all waves done reading Xsh (full drain)

#pragma unroll
    for (int i = 0; i < 8; ++i) {
      int ch = i * 256 + t;
      int row = ch >> 4, c = ch & 15;
      int byte = (row * 256 + c * 16) ^ ((row & 7) << 4);
      *reinterpret_cast<bf16x8*>((char*)Xsh + byte) = xr[i];
    }

    __syncthreads();                    // Xsh visible to all waves

    if (it < 7) {
#pragma unroll
      for (int i = 0; i < 8; ++i) {
        int ch = i * 256 + t;
        int row = ch >> 4, c = ch & 15;
        xr[i] = *reinterpret_cast<const bf16x8*>(
            XA + ((size_t)(b * MXN + (mt + 1) * 128 + row) * KP + c * 8));
      }
    }

    f32x4 acc[2][2];
#pragma unroll
    for (int i = 0; i < 2; ++i)
#pragma unroll
      for (int j = 0; j < 2; ++j) acc[i][j] = (f32x4){0.f, 0.f, 0.f, 0.f};

#pragma unroll
    for (int ks = 0; ks < 4; ++ks) {
      const int d2 = ks * 64 + lk * 2;   // byte offset within row
      int rm0 = m_w + lr, rm1 = m_w + 16 + lr;
      bf16x8 b0 = *reinterpret_cast<bf16x8*>(
          (char*)Xsh + ((rm0 * 256 + d2) ^ ((rm0 & 7) << 4)));
      bf16x8 b1 = *reinterpret_cast<bf16x8*>(
          (char*)Xsh + ((rm1 * 256 + d2) ^ ((rm1 & 7) << 4)));
      acc[0][0] = __builtin_amdgcn_mfma_f32_16x16x32_bf16(yf[0][ks], b0, acc[0][0], 0, 0, 0);
      acc[0][1] = __builtin_amdgcn_mfma_f32_16x16x32_bf16(yf[0][ks], b1, acc[0][1], 0, 0, 0);
      acc[1][0] = __builtin_amdgcn_mfma_f32_16x16x32_bf16(yf[1][ks], b0, acc[1][0], 0, 0, 0);
      acc[1][1] = __builtin_amdgcn_mfma_f32_16x16x32_bf16(yf[1][ks], b1, acc[1][1], 0, 0, 0);
    }

    float sx0 = sqX[b * MXN + mt * 128 + m_w + lr];
    float sx1 = sqX[b * MXN + mt * 128 + m_w + 16 + lr];
#pragma unroll
    for (int i = 0; i < 2; ++i)
#pragma unroll
      for (int reg = 0; reg < 4; ++reg) {
        int n = n0 + i * 16 + ((l >> 4) << 2) + reg;
        size_t obase = ((size_t)b * MXN + n) * MXN + mt * 128 + m_w;
        float v0 = syv[i][reg] + sx0 - 2.0f * acc[i][0][reg];
        float v1 = syv[i][reg] + sx1 - 2.0f * acc[i][1][reg];
        out[obase + lr]      = v0 > 0.f ? v0 : 0.f;
        out[obase + 16 + lr] = v1 > 0.f ? v1 : 0.f;
      }
  }
}

extern "C" void kernel_launch(void* const* d_in, const int* in_sizes, int n_in,
                              void* d_out, int out_size, void* d_ws, size_t ws_size,
                              hipStream_t stream) {
  const float* X = (const float*)d_in[0];   // (8, 2048, 256)
  const float* Y = (const float*)d_in[1];   // (8, 2048, 256)
  const float* A = (const float*)d_in[2];   // (256, 100)
  float* out = (float*)d_out;               // (8, 2048, 2048)

  char* ws = (char*)d_ws;
  const size_t ROWS = (size_t)NB * MXN;     // 16384
  unsigned short* XAw = (unsigned short*)ws;                        // 4 MB
  unsigned short* YAw = (unsigned short*)(ws + ROWS * KP * 2);      // 4 MB
  float* sqX = (float*)(ws + 2 * ROWS * KP * 2);                    // 64 KB
  float* sqY = (float*)(ws + 2 * ROWS * KP * 2 + ROWS * 4);         // 64 KB

  k_proj<<<512, 256, 0, stream>>>(X, Y, A, XAw, YAw, sqX, sqY);
  k_cross<<<1024, 256, 0, stream>>>(XAw, YAw, sqX, sqY, out);
}